// Round 4
// baseline (52.178 us; speedup 1.0000x reference)
//
#include <hip/hip_runtime.h>

// KDA state update:
//   S_decay = alpha[:,None] * S
//   kT_S[e] = sum_d k[d] * S_decay[d][e]
//   S_new   = S_decay + beta * outer(k, v - kT_S)
//   o[e]    = sum_d q[d] * S_new[d][e]
//
// B=64, H=32, DK=DV=128. One block per (b,h) head; 512 threads.
// Each thread owns an 8-row x 4-col register tile of S (32 floats) so S is
// fetched from HBM exactly once, with VGPR<=64 -> 8 waves/SIMD (full occupancy)
// for latency hiding. All global loads/stores are float4-coalesced.
// Sout stores are NONTEMPORAL (never re-read; keep L3 for S residency).

#define DK 128
#define DV 128

typedef float v4f __attribute__((ext_vector_type(4)));

__global__ __launch_bounds__(512, 8) void kda_update_kernel(
    const float* __restrict__ S,
    const float* __restrict__ k,
    const float* __restrict__ v,
    const float* __restrict__ q,
    const float* __restrict__ alpha,
    const float* __restrict__ beta,
    float* __restrict__ Sout,
    float* __restrict__ o)
{
    const int bh   = blockIdx.x;
    const int tid  = threadIdx.x;
    const int col4 = (tid & 31) * 4;   // starting column e of this thread's 4 cols
    const int rgrp = tid >> 5;         // 0..15 : owns rows rgrp*8 .. rgrp*8+7

    __shared__ float sk[DK];
    __shared__ float sa[DK];
    __shared__ float sq[DK];
    __shared__ float sak[DK];          // alpha[d]*k[d]
    __shared__ float scoef[DV];
    __shared__ float red[16][DV];

    const size_t head_off = (size_t)bh * DK * DV;
    const float* __restrict__ Sbh = S + head_off;

    // Stage per-head vectors into LDS.
    if (tid < DK) {
        const float kk = k[(size_t)bh * DK + tid];
        const float aa = alpha[(size_t)bh * DK + tid];
        sk[tid]  = kk;
        sa[tid]  = aa;
        sak[tid] = kk * aa;
        sq[tid]  = q[(size_t)bh * DK + tid];
    }
    __syncthreads();

    // ---- Pass 1: load S tile into registers, accumulate partial k^T(alpha*S)
    float s_reg[8][4];
    float part0 = 0.f, part1 = 0.f, part2 = 0.f, part3 = 0.f;
    const int d0 = rgrp * 8;

    #pragma unroll
    for (int i = 0; i < 8; ++i) {
        const int d = d0 + i;
        const v4f sv = *reinterpret_cast<const v4f*>(Sbh + (size_t)d * DV + col4);
        s_reg[i][0] = sv.x; s_reg[i][1] = sv.y; s_reg[i][2] = sv.z; s_reg[i][3] = sv.w;
        const float ak = sak[d];
        part0 += ak * sv.x;
        part1 += ak * sv.y;
        part2 += ak * sv.z;
        part3 += ak * sv.w;
    }

    red[rgrp][col4 + 0] = part0;
    red[rgrp][col4 + 1] = part1;
    red[rgrp][col4 + 2] = part2;
    red[rgrp][col4 + 3] = part3;
    __syncthreads();

    // Reduce 16 row-group partials -> kT_S[e]; coef[e] = beta*(v[e]-kT_S[e]).
    if (tid < DV) {
        float s = 0.f;
        #pragma unroll
        for (int g = 0; g < 16; ++g) s += red[g][tid];
        const float b = beta[bh];
        scoef[tid] = b * (v[(size_t)bh * DV + tid] - s);
    }
    __syncthreads();

    const float c0 = scoef[col4 + 0];
    const float c1 = scoef[col4 + 1];
    const float c2 = scoef[col4 + 2];
    const float c3 = scoef[col4 + 3];

    // ---- Pass 2: S_new = alpha[d]*S + k[d]*coef[e]; write (nt); accumulate o.
    float o0 = 0.f, o1 = 0.f, o2 = 0.f, o3 = 0.f;
    float* __restrict__ Sobh = Sout + head_off;

    #pragma unroll
    for (int i = 0; i < 8; ++i) {
        const int d = d0 + i;
        const float a  = sa[d];
        const float kk = sk[d];
        const float qq = sq[d];
        v4f ov;
        ov.x = a * s_reg[i][0] + kk * c0;
        ov.y = a * s_reg[i][1] + kk * c1;
        ov.z = a * s_reg[i][2] + kk * c2;
        ov.w = a * s_reg[i][3] + kk * c3;
        __builtin_nontemporal_store(ov, reinterpret_cast<v4f*>(Sobh + (size_t)d * DV + col4));
        o0 += qq * ov.x;
        o1 += qq * ov.y;
        o2 += qq * ov.z;
        o3 += qq * ov.w;
    }

    red[rgrp][col4 + 0] = o0;
    red[rgrp][col4 + 1] = o1;
    red[rgrp][col4 + 2] = o2;
    red[rgrp][col4 + 3] = o3;
    __syncthreads();

    if (tid < DV) {
        float s = 0.f;
        #pragma unroll
        for (int g = 0; g < 16; ++g) s += red[g][tid];
        o[(size_t)bh * DV + tid] = s;
    }
}

extern "C" void kernel_launch(void* const* d_in, const int* in_sizes, int n_in,
                              void* d_out, int out_size, void* d_ws, size_t ws_size,
                              hipStream_t stream) {
    const float* S     = (const float*)d_in[0];
    const float* k     = (const float*)d_in[1];
    const float* v     = (const float*)d_in[2];
    const float* q     = (const float*)d_in[3];
    const float* alpha = (const float*)d_in[4];
    const float* beta  = (const float*)d_in[5];

    const int BH = in_sizes[5];  // beta has B*H elements -> 2048 heads

    float* Sout = (float*)d_out;
    float* o    = Sout + (size_t)BH * DK * DV;

    kda_update_kernel<<<dim3(BH), dim3(512), 0, stream>>>(S, k, v, q, alpha, beta, Sout, o);
}

// Round 5
// 44.465 us; speedup vs baseline: 1.1734x; 1.1734x over previous
//
#include <hip/hip_runtime.h>

// KDA state update:
//   coef[e] = beta * (v[e] - sum_d alpha[d]*k[d]*S[d][e])
//   S_new[d][e] = alpha[d]*S[d][e] + k[d]*coef[e]
//   o[e]    = sum_d q[d] * S_new[d][e]
//
// B=64, H=32, DK=DV=128. One block (128 threads) per head; thread e owns
// COLUMN e of S: all reductions (over d) are thread-local, so there are no
// cross-thread reduce phases and only ONE barrier (after vector staging).
// Each thread holds its 128-element S column in VGPRs: S is read from HBM
// exactly once. Loads/stores are coalesced across threads (consecutive e).
// Sout stores are nontemporal (never re-read; keep L3 for S residency).

#define DK 128
#define DV 128

__global__ __launch_bounds__(128) void kda_update_kernel(
    const float* __restrict__ S,
    const float* __restrict__ k,
    const float* __restrict__ v,
    const float* __restrict__ q,
    const float* __restrict__ alpha,
    const float* __restrict__ beta,
    float* __restrict__ Sout,
    float* __restrict__ o)
{
    const int bh = blockIdx.x;
    const int e  = threadIdx.x;        // column index 0..127

    __shared__ float sak[DK];          // alpha[d]*k[d]
    __shared__ float sa[DK];
    __shared__ float sk[DK];
    __shared__ float sq[DK];

    const size_t hoff = (size_t)bh * DK * DV;
    const float* __restrict__ Sbh = S + hoff;

    // Stage per-head vectors into LDS (one element per thread).
    {
        const float kk = k[(size_t)bh * DK + e];
        const float aa = alpha[(size_t)bh * DK + e];
        sk[e]  = kk;
        sa[e]  = aa;
        sak[e] = kk * aa;
        sq[e]  = q[(size_t)bh * DK + e];
    }
    __syncthreads();

    // ---- Pass 1: load column e of S into registers (128 independent loads),
    //              accumulate kts = sum_d ak[d]*S[d][e] thread-locally.
    float s_col[DK];
    float kts = 0.f;
    #pragma unroll
    for (int d = 0; d < DK; ++d) {
        s_col[d] = Sbh[(size_t)d * DV + e];
        kts += sak[d] * s_col[d];
    }

    const float coef = beta[bh] * (v[(size_t)bh * DV + e] - kts);

    // ---- Pass 2: S_new column from registers; nt-store; accumulate o[e].
    float oacc = 0.f;
    float* __restrict__ Sobh = Sout + hoff;
    #pragma unroll
    for (int d = 0; d < DK; ++d) {
        const float sn = sa[d] * s_col[d] + sk[d] * coef;
        __builtin_nontemporal_store(sn, Sobh + (size_t)d * DV + e);
        oacc += sq[d] * sn;
    }

    o[(size_t)bh * DV + e] = oacc;
}

extern "C" void kernel_launch(void* const* d_in, const int* in_sizes, int n_in,
                              void* d_out, int out_size, void* d_ws, size_t ws_size,
                              hipStream_t stream) {
    const float* S     = (const float*)d_in[0];
    const float* k     = (const float*)d_in[1];
    const float* v     = (const float*)d_in[2];
    const float* q     = (const float*)d_in[3];
    const float* alpha = (const float*)d_in[4];
    const float* beta  = (const float*)d_in[5];

    const int BH = in_sizes[5];  // beta has B*H elements -> 2048 heads

    float* Sout = (float*)d_out;
    float* o    = Sout + (size_t)BH * DK * DV;

    kda_update_kernel<<<dim3(BH), dim3(128), 0, stream>>>(S, k, v, q, alpha, beta, Sout, o);
}